// Round 11
// baseline (467.543 us; speedup 1.0000x reference)
//
#include <hip/hip_runtime.h>

typedef unsigned short u16;
typedef u16 u16x2 __attribute__((ext_vector_type(2)));
typedef u16 u16x4 __attribute__((ext_vector_type(4)));
typedef u16 u16x8 __attribute__((ext_vector_type(8)));
typedef __bf16 bf16x8 __attribute__((ext_vector_type(8)));
typedef float f32x4 __attribute__((ext_vector_type(4)));
typedef float f32x2 __attribute__((ext_vector_type(2)));

#define MFMA16(A, B, C) __builtin_amdgcn_mfma_f32_16x16x32_bf16(A, B, C, 0, 0, 0)

// Constants: B=2, S=2048, E=512, H=8, HD=64
#define SB 2
#define SS 2048
#define SE 512
#define SH 8
#define SHD 64

// Hardware RNE f32->bf16.
__device__ __forceinline__ u16 f2b(float f) {
  return __builtin_bit_cast(u16, (__bf16)f);
}

__device__ __forceinline__ bf16x8 as_bf16x8(u16x8 v) {
  return __builtin_bit_cast(bf16x8, v);
}

// ---------------------------------------------------------------------------
// Merged prep: blocks [0,2048) convert X f32->bf16; blocks [2048,2816)
// transpose+convert Wqkv into WqkvT [1536,512] bf16.  (UNCHANGED — control)
// ---------------------------------------------------------------------------
__global__ __launch_bounds__(256)
void prep_kernel(const float* __restrict__ X, u16* __restrict__ Xb,
                 const float* __restrict__ Wqkv, u16* __restrict__ WqkvT)
{
  __shared__ float t[32][33];
  const int tid = threadIdx.x;
  if (blockIdx.x < 2048) {
    const int i = (blockIdx.x * 256 + tid) * 4;
    const float4 v = *(const float4*)&X[i];
    u16x4 o;
    o[0] = f2b(v.x); o[1] = f2b(v.y); o[2] = f2b(v.z); o[3] = f2b(v.w);
    *(u16x4*)&Xb[i] = o;
  } else {
    const int bx = blockIdx.x - 2048;          // 768 blocks: 48 n x 16 k
    const int n0 = (bx % 48) * 32, k0 = (bx / 48) * 32;
    const int r = tid >> 3, c4 = (tid & 7) * 4;
    const float4 v = *(const float4*)&Wqkv[(size_t)(k0 + r) * 1536 + n0 + c4];
    t[r][c4 + 0] = v.x; t[r][c4 + 1] = v.y; t[r][c4 + 2] = v.z; t[r][c4 + 3] = v.w;
    __syncthreads();
    u16x4 o;
    o[0] = f2b(t[c4 + 0][r]);
    o[1] = f2b(t[c4 + 1][r]);
    o[2] = f2b(t[c4 + 2][r]);
    o[3] = f2b(t[c4 + 3][r]);
    *(u16x4*)&WqkvT[(n0 + r) * 512 + k0 + c4] = o;
  }
}

// ---------------------------------------------------------------------------
// Standalone W transpose (used post-attn for WoT).  (UNCHANGED)
// ---------------------------------------------------------------------------
__global__ __launch_bounds__(256)
void wtrans_kernel(const float* __restrict__ in, u16* __restrict__ out, int N)
{
  __shared__ float t[32][33];
  const int tid = threadIdx.x;
  const int r = tid >> 3, c4 = (tid & 7) * 4;
  const int k0 = blockIdx.y * 32, n0 = blockIdx.x * 32;
  const float4 v = *(const float4*)&in[(size_t)(k0 + r) * N + n0 + c4];
  t[r][c4 + 0] = v.x; t[r][c4 + 1] = v.y; t[r][c4 + 2] = v.z; t[r][c4 + 3] = v.w;
  __syncthreads();
  u16x4 o;
  o[0] = f2b(t[c4 + 0][r]);
  o[1] = f2b(t[c4 + 1][r]);
  o[2] = f2b(t[c4 + 2][r]);
  o[3] = f2b(t[c4 + 3][r]);
  *(u16x4*)&out[(n0 + r) * 512 + k0 + c4] = o;
}

// ---------------------------------------------------------------------------
// Unified bf16 GEMM (UNCHANGED — control).
// ---------------------------------------------------------------------------
template <int MODE>
__global__ __launch_bounds__(256, 2)
void gemm_kernel(const u16* __restrict__ A, const u16* __restrict__ Bt,
                 const float* __restrict__ bias,
                 u16* __restrict__ Q, u16* __restrict__ K, u16* __restrict__ Vt,
                 float* __restrict__ Out)
{
  __shared__ __align__(16) u16 As[128 * 40];
  __shared__ __align__(16) u16 Bs[128 * 40];
  const int tid  = threadIdx.x;
  const int lane = tid & 63, wave = tid >> 6, quad = lane >> 4, l16 = lane & 15;
  const int m0 = blockIdx.y * 128, n0 = blockIdx.x * 128;
  const int wr = (wave >> 1) * 64, wc = (wave & 1) * 64;
  const int sr = tid >> 2, sc = (tid & 3) * 8;

  const f32x4 z4 = {0.f, 0.f, 0.f, 0.f};
  f32x4 acc[4][4];
#pragma unroll
  for (int i = 0; i < 4; i++)
#pragma unroll
    for (int j = 0; j < 4; j++) acc[i][j] = z4;

  for (int k0 = 0; k0 < 512; k0 += 32) {
    const u16x8 a0 = *(const u16x8*)&A[(m0 + sr) * 512 + k0 + sc];
    const u16x8 a1 = *(const u16x8*)&A[(m0 + 64 + sr) * 512 + k0 + sc];
    const u16x8 b0 = *(const u16x8*)&Bt[(n0 + sr) * 512 + k0 + sc];
    const u16x8 b1 = *(const u16x8*)&Bt[(n0 + 64 + sr) * 512 + k0 + sc];
    __syncthreads();
    *(u16x8*)&As[sr * 40 + sc]        = a0;
    *(u16x8*)&As[(64 + sr) * 40 + sc] = a1;
    *(u16x8*)&Bs[sr * 40 + sc]        = b0;
    *(u16x8*)&Bs[(64 + sr) * 40 + sc] = b1;
    __syncthreads();
    bf16x8 af[4], bf[4];
#pragma unroll
    for (int i = 0; i < 4; i++) {
      af[i] = as_bf16x8(*(const u16x8*)&As[(wr + i * 16 + l16) * 40 + quad * 8]);
      bf[i] = as_bf16x8(*(const u16x8*)&Bs[(wc + i * 16 + l16) * 40 + quad * 8]);
    }
#pragma unroll
    for (int i = 0; i < 4; i++)
#pragma unroll
      for (int j = 0; j < 4; j++) acc[i][j] = MFMA16(af[i], bf[j], acc[i][j]);
  }

#pragma unroll
  for (int tm = 0; tm < 4; tm++) {
#pragma unroll
    for (int tn = 0; tn < 4; tn++) {
#pragma unroll
      for (int r = 0; r < 4; r++) {
        const int gm = m0 + wr + tm * 16 + quad * 4 + r;
        const int gn = n0 + wc + tn * 16 + l16;
        const float v = acc[tm][tn][r] + bias[gn];
        if (MODE == 0) {
          const int bb = gm >> 11, s = gm & 2047;
          const int hh = gn / 192, j = gn - hh * 192;
          const int bh = bb * SH + hh;
          if (j < 64)
            Q[(bh * SS + s) * SHD + j] = f2b(v * 0.125f);
          else if (j < 128)
            K[(bh * SS + s) * SHD + (j - 64)] = f2b(v);
          else
            Vt[(bh * SHD + (j - 128)) * SS + s] = f2b(v);
        } else {
          Out[gm * 512 + gn] = v;
        }
      }
    }
  }
}

// ---------------------------------------------------------------------------
// Fused attention v10: STREAMING TWO-PASS — registers and occupancy, not
// store mechanics (R5/R7/R8/R9/R10 all ~null on store-path changes).
//   Old structure kept acc[16] (64 VGPR) live for the whole kernel ->
//   live set ~127 vs the 128 cap (spill; R3's profiled variant reported
//   VGPR=60 with 64 live floats = definitely spilled) and 68 KB LDS ->
//   2 blocks/CU (16 waves/CU).
// v10: 8 waves, wave w owns keys [w*256,+256) of a 16-row q-tile:
//   pass A: stream QK^T tiles, keep ONLY online (m,l)  (~12 live regs);
//           cross-lane (xor16/32) + cross-wave merge  [barrier #1]
//   pass B: recompute each score tile (K is L2-hot; +32 MFMA/wave is ~3us
//           chip-wide), p=exp(c-mg)*inv -> fp32 f32x4 global store + bf16 LDS
//           immediately; tile dies. PV per 128-key half-strip from ONE
//           reused 16x136 LDS region per wave (wave-private, in-order DS).
//   O partials -> own LDS region  [barrier #2] -> cross-wave reduce.
// LDS 35 KB (was 68), launch_bounds(512,6) caps VGPR at 85 (est peak ~75)
// -> 24 waves/CU (was 16), zero spill; stores spread through pass B overlap
// PV compute. m is bit-identical (exact max); l changes association order
// only (~1e-7 rel).
// ---------------------------------------------------------------------------
#define PSTR2 136            // u16 stride per row (128 keys + 8 pad), 272 B
#define PWAVE2 (16 * PSTR2)  // 2176 u16 = 4352 B per wave
#define OSTR2 68             // f32 stride for O-partial staging (272 B rows)

__global__ __launch_bounds__(512, 6)
void attn_kernel(const u16* __restrict__ Q, const u16* __restrict__ K,
                 const u16* __restrict__ Vt, u16* __restrict__ values,
                 float* __restrict__ attn)
{
  __shared__ __align__(16) u16 p_lds[8 * PWAVE2];  // 34,816 B
  __shared__ float srm[8][16];
  __shared__ float srl[8][16];

  const int tid  = threadIdx.x;
  const int lane = tid & 63, wave = tid >> 6, quad = lane >> 4, l16 = lane & 15;

  // XCD swizzle (kept; harmless per R8): 2 (b,h) pairs per XCD
  const int bid = blockIdx.x;
  const int wg  = (bid & 7) * 256 + (bid >> 3);
  const int qt  = wg & 127;        // q-tile (16 rows)
  const int bh  = wg >> 7;         // 0..15
  const int h = bh & 7, b = bh >> 3;
  const int q0 = qt * 16;

  const u16* Qb = Q + (size_t)bh * SS * SHD;
  const u16* Kb = K + (size_t)bh * SS * SHD;
  const u16* Vb = Vt + (size_t)bh * SHD * SS;

  // Q fragments (B-operand; lane layout same as A-operand)
  const bf16x8 aq0 = as_bf16x8(*(const u16x8*)&Qb[(q0 + l16) * SHD + quad * 8]);
  const bf16x8 aq1 = as_bf16x8(*(const u16x8*)&Qb[(q0 + l16) * SHD + 32 + quad * 8]);

  // ---- pass A: streaming online (m,l); scores discarded ----
  float m = -1e30f, l = 0.f;
  for (int ct = 0; ct < 16; ct++) {
    const int kb = wave * 256 + ct * 16;
    bf16x8 bk0 = as_bf16x8(*(const u16x8*)&Kb[(kb + l16) * SHD + quad * 8]);
    bf16x8 bk1 = as_bf16x8(*(const u16x8*)&Kb[(kb + l16) * SHD + 32 + quad * 8]);
    f32x4 c = {0.f, 0.f, 0.f, 0.f};
    c = MFMA16(bk0, aq0, c);   // SWAPPED: lane holds S[q=l16][4 consecutive keys]
    c = MFMA16(bk1, aq1, c);
    const float tm = fmaxf(fmaxf(c[0], c[1]), fmaxf(c[2], c[3]));
    const float mn = fmaxf(m, tm);
    const float s = (__expf(c[0] - mn) + __expf(c[1] - mn)) +
                    (__expf(c[2] - mn) + __expf(c[3] - mn));
    l = l * __expf(m - mn) + s;
    m = mn;
  }
  // cross-lane merge over the 4 quads holding the same q-row (xor 16, 32)
#pragma unroll
  for (int off = 16; off <= 32; off <<= 1) {
    const float m2 = __shfl_xor(m, off);
    const float l2 = __shfl_xor(l, off);
    const float mn = fmaxf(m, m2);
    l = l * __expf(m - mn) + l2 * __expf(m2 - mn);
    m = mn;
  }
  if (lane < 16) {   // quad == 0
    srm[wave][l16] = m;
    srl[wave][l16] = l;
  }
  __syncthreads();  // barrier #1

  // ---- global merge ----
  float mg = srm[0][l16];
#pragma unroll
  for (int w = 1; w < 8; w++) mg = fmaxf(mg, srm[w][l16]);
  float lg = 0.f;
#pragma unroll
  for (int w = 0; w < 8; w++) lg += srl[w][l16] * __expf(srm[w][l16] - mg);
  const float inv = 1.f / lg;

  // ---- pass B: recompute scores -> P stores + LDS -> PV per half-strip ----
  u16* pl = &p_lds[wave * PWAVE2];
  float* attn_b = attn + ((size_t)bh * SS + q0) * SS;
  f32x4 oacc[4];
#pragma unroll
  for (int nt = 0; nt < 4; nt++) oacc[nt] = (f32x4){0.f, 0.f, 0.f, 0.f};

#pragma unroll
  for (int half = 0; half < 2; half++) {
#pragma unroll
    for (int ct8 = 0; ct8 < 8; ct8++) {
      const int ct = half * 8 + ct8;
      const int kb = wave * 256 + ct * 16;
      bf16x8 bk0 = as_bf16x8(*(const u16x8*)&Kb[(kb + l16) * SHD + quad * 8]);
      bf16x8 bk1 = as_bf16x8(*(const u16x8*)&Kb[(kb + l16) * SHD + 32 + quad * 8]);
      f32x4 c = {0.f, 0.f, 0.f, 0.f};
      c = MFMA16(bk0, aq0, c);
      c = MFMA16(bk1, aq1, c);
      f32x4 p;
      u16x4 t;
#pragma unroll
      for (int r = 0; r < 4; r++) {
        p[r] = __expf(c[r] - mg) * inv;
        t[r] = f2b(p[r]);
      }
      *(f32x4*)&attn_b[l16 * SS + ct * 16 + wave * 256 + quad * 4] = p;
      *(u16x4*)&pl[l16 * PSTR2 + ct8 * 16 + quad * 4] = t;
    }
    // PV over this 128-key half (wave-private LDS, in-order DS; region
    // reused across halves — WAR handled by per-wave DS ordering)
#pragma unroll
    for (int kc = 0; kc < 4; kc++) {
      bf16x8 pa = as_bf16x8(*(const u16x8*)&pl[l16 * PSTR2 + kc * 32 + quad * 8]);
      const int sb = wave * 256 + half * 128 + kc * 32 + quad * 8;
#pragma unroll
      for (int nt = 0; nt < 4; nt++) {
        bf16x8 vb = as_bf16x8(*(const u16x8*)&Vb[(nt * 16 + l16) * SS + sb]);
        oacc[nt] = MFMA16(vb, pa, oacc[nt]);  // O[q=l16][d]
      }
    }
  }

  // ---- O partials [q][d] into own LDS region (4x ds_write_b128) ----
  float* op = (float*)pl;  // 16*OSTR2*4 = 4352 B = exactly the wave region
#pragma unroll
  for (int nt = 0; nt < 4; nt++)
    *(f32x4*)&op[l16 * OSTR2 + nt * 16 + quad * 4] = oacc[nt];
  __syncthreads();  // barrier #2

  // ---- cross-wave reduce + values write ----
  const int q = tid >> 5, d0 = (tid & 31) * 2;
  f32x2 s2 = {0.f, 0.f};
#pragma unroll
  for (int w = 0; w < 8; w++) {
    const float* opw = (const float*)&p_lds[w * PWAVE2];
    s2 += *(const f32x2*)&opw[q * OSTR2 + d0];
  }
  u16x2 o2;
  o2[0] = f2b(s2[0]);
  o2[1] = f2b(s2[1]);
  *(u16x2*)&values[((size_t)(b * SS + q0 + q) * SH + h) * SHD + d0] = o2;
}

// ---------------------------------------------------------------------------
// Workspace budget: EXACTLY 16 MiB (verified footprint).
//   ws: Q(4MB) K(4MB) Vt(4MB) values(4MB; Xb aliases it)
//   WqkvT: staged in d_out's attn region (dead until attn_kernel overwrites).
//   WoT:   aliases Q region; produced AFTER attn (Q dead), read by oproj.
// ---------------------------------------------------------------------------
extern "C" void kernel_launch(void* const* d_in, const int* in_sizes, int n_in,
                              void* d_out, int out_size, void* d_ws, size_t ws_size,
                              hipStream_t stream) {
  const float* X    = (const float*)d_in[0];
  const float* Wqkv = (const float*)d_in[1];
  const float* bqkv = (const float*)d_in[2];
  const float* Wo   = (const float*)d_in[3];
  const float* bo   = (const float*)d_in[4];

  float* o_out    = (float*)d_out;                       // [2,2048,512]
  float* attn_out = o_out + SB * SS * SE;                // [2,8,2048,2048]

  const size_t QKV_ELEMS = (size_t)SB * SH * SS * SHD;   // 2,097,152 per tensor
  u16* Q      = (u16*)d_ws;
  u16* K      = Q + QKV_ELEMS;
  u16* Vt     = K + QKV_ELEMS;
  u16* values = Vt + QKV_ELEMS;
  u16* Xb     = values;               // dead before attn writes values
  u16* WqkvT  = (u16*)attn_out;       // dead until attn writes attn_out
  u16* WoT    = Q;                    // Q dead after attn; WoT made post-attn

  // Merged prep: X conversion + Wqkv transpose (one launch)
  prep_kernel<<<dim3(2816), 256, 0, stream>>>(X, Xb, Wqkv, WqkvT);

  // QKV projection: M=4096 (32 m-blocks), N=1536 (12 n-blocks)
  gemm_kernel<0><<<dim3(12, 32), 256, 0, stream>>>(Xb, WqkvT, bqkv, Q, K, Vt, nullptr);
  // Attention: 2048 blocks, XCD-swizzled, streaming two-pass
  attn_kernel<<<dim3(2048), 512, 0, stream>>>(Q, K, Vt, values, attn_out);
  // Wo transpose into (now-dead) Q region, then O projection
  wtrans_kernel<<<dim3(16, 16), 256, 0, stream>>>(Wo, WoT, 512);
  gemm_kernel<1><<<dim3(4, 32), 256, 0, stream>>>(values, WoT, bo,
                                                  nullptr, nullptr, nullptr, o_out);
}

// Round 12
// 415.658 us; speedup vs baseline: 1.1248x; 1.1248x over previous
//
#include <hip/hip_runtime.h>

typedef unsigned short u16;
typedef u16 u16x2 __attribute__((ext_vector_type(2)));
typedef u16 u16x4 __attribute__((ext_vector_type(4)));
typedef u16 u16x8 __attribute__((ext_vector_type(8)));
typedef __bf16 bf16x8 __attribute__((ext_vector_type(8)));
typedef float f32x4 __attribute__((ext_vector_type(4)));
typedef float f32x2 __attribute__((ext_vector_type(2)));

#define MFMA16(A, B, C) __builtin_amdgcn_mfma_f32_16x16x32_bf16(A, B, C, 0, 0, 0)

// Constants: B=2, S=2048, E=512, H=8, HD=64
#define SB 2
#define SS 2048
#define SE 512
#define SH 8
#define SHD 64

// Hardware RNE f32->bf16.
__device__ __forceinline__ u16 f2b(float f) {
  return __builtin_bit_cast(u16, (__bf16)f);
}

__device__ __forceinline__ bf16x8 as_bf16x8(u16x8 v) {
  return __builtin_bit_cast(bf16x8, v);
}

// ---------------------------------------------------------------------------
// Merged prep: blocks [0,2048) convert X f32->bf16; blocks [2048,2816)
// transpose+convert Wqkv into WqkvT [1536,512] bf16.  (UNCHANGED)
// ---------------------------------------------------------------------------
__global__ __launch_bounds__(256)
void prep_kernel(const float* __restrict__ X, u16* __restrict__ Xb,
                 const float* __restrict__ Wqkv, u16* __restrict__ WqkvT)
{
  __shared__ float t[32][33];
  const int tid = threadIdx.x;
  if (blockIdx.x < 2048) {
    const int i = (blockIdx.x * 256 + tid) * 4;
    const float4 v = *(const float4*)&X[i];
    u16x4 o;
    o[0] = f2b(v.x); o[1] = f2b(v.y); o[2] = f2b(v.z); o[3] = f2b(v.w);
    *(u16x4*)&Xb[i] = o;
  } else {
    const int bx = blockIdx.x - 2048;          // 768 blocks: 48 n x 16 k
    const int n0 = (bx % 48) * 32, k0 = (bx / 48) * 32;
    const int r = tid >> 3, c4 = (tid & 7) * 4;
    const float4 v = *(const float4*)&Wqkv[(size_t)(k0 + r) * 1536 + n0 + c4];
    t[r][c4 + 0] = v.x; t[r][c4 + 1] = v.y; t[r][c4 + 2] = v.z; t[r][c4 + 3] = v.w;
    __syncthreads();
    u16x4 o;
    o[0] = f2b(t[c4 + 0][r]);
    o[1] = f2b(t[c4 + 1][r]);
    o[2] = f2b(t[c4 + 2][r]);
    o[3] = f2b(t[c4 + 3][r]);
    *(u16x4*)&WqkvT[(n0 + r) * 512 + k0 + c4] = o;
  }
}

// ---------------------------------------------------------------------------
// Standalone W transpose (used post-attn for WoT).  (UNCHANGED)
// ---------------------------------------------------------------------------
__global__ __launch_bounds__(256)
void wtrans_kernel(const float* __restrict__ in, u16* __restrict__ out, int N)
{
  __shared__ float t[32][33];
  const int tid = threadIdx.x;
  const int r = tid >> 3, c4 = (tid & 7) * 4;
  const int k0 = blockIdx.y * 32, n0 = blockIdx.x * 32;
  const float4 v = *(const float4*)&in[(size_t)(k0 + r) * N + n0 + c4];
  t[r][c4 + 0] = v.x; t[r][c4 + 1] = v.y; t[r][c4 + 2] = v.z; t[r][c4 + 3] = v.w;
  __syncthreads();
  u16x4 o;
  o[0] = f2b(t[c4 + 0][r]);
  o[1] = f2b(t[c4 + 1][r]);
  o[2] = f2b(t[c4 + 2][r]);
  o[3] = f2b(t[c4 + 3][r]);
  *(u16x4*)&out[(n0 + r) * 512 + k0 + c4] = o;
}

// ---------------------------------------------------------------------------
// Unified bf16 GEMM (UNCHANGED — control).
// ---------------------------------------------------------------------------
template <int MODE>
__global__ __launch_bounds__(256, 2)
void gemm_kernel(const u16* __restrict__ A, const u16* __restrict__ Bt,
                 const float* __restrict__ bias,
                 u16* __restrict__ Q, u16* __restrict__ K, u16* __restrict__ Vt,
                 float* __restrict__ Out)
{
  __shared__ __align__(16) u16 As[128 * 40];
  __shared__ __align__(16) u16 Bs[128 * 40];
  const int tid  = threadIdx.x;
  const int lane = tid & 63, wave = tid >> 6, quad = lane >> 4, l16 = lane & 15;
  const int m0 = blockIdx.y * 128, n0 = blockIdx.x * 128;
  const int wr = (wave >> 1) * 64, wc = (wave & 1) * 64;
  const int sr = tid >> 2, sc = (tid & 3) * 8;

  const f32x4 z4 = {0.f, 0.f, 0.f, 0.f};
  f32x4 acc[4][4];
#pragma unroll
  for (int i = 0; i < 4; i++)
#pragma unroll
    for (int j = 0; j < 4; j++) acc[i][j] = z4;

  for (int k0 = 0; k0 < 512; k0 += 32) {
    const u16x8 a0 = *(const u16x8*)&A[(m0 + sr) * 512 + k0 + sc];
    const u16x8 a1 = *(const u16x8*)&A[(m0 + 64 + sr) * 512 + k0 + sc];
    const u16x8 b0 = *(const u16x8*)&Bt[(n0 + sr) * 512 + k0 + sc];
    const u16x8 b1 = *(const u16x8*)&Bt[(n0 + 64 + sr) * 512 + k0 + sc];
    __syncthreads();
    *(u16x8*)&As[sr * 40 + sc]        = a0;
    *(u16x8*)&As[(64 + sr) * 40 + sc] = a1;
    *(u16x8*)&Bs[sr * 40 + sc]        = b0;
    *(u16x8*)&Bs[(64 + sr) * 40 + sc] = b1;
    __syncthreads();
    bf16x8 af[4], bf[4];
#pragma unroll
    for (int i = 0; i < 4; i++) {
      af[i] = as_bf16x8(*(const u16x8*)&As[(wr + i * 16 + l16) * 40 + quad * 8]);
      bf[i] = as_bf16x8(*(const u16x8*)&Bs[(wc + i * 16 + l16) * 40 + quad * 8]);
    }
#pragma unroll
    for (int i = 0; i < 4; i++)
#pragma unroll
      for (int j = 0; j < 4; j++) acc[i][j] = MFMA16(af[i], bf[j], acc[i][j]);
  }

#pragma unroll
  for (int tm = 0; tm < 4; tm++) {
#pragma unroll
    for (int tn = 0; tn < 4; tn++) {
#pragma unroll
      for (int r = 0; r < 4; r++) {
        const int gm = m0 + wr + tm * 16 + quad * 4 + r;
        const int gn = n0 + wc + tn * 16 + l16;
        const float v = acc[tm][tn][r] + bias[gn];
        if (MODE == 0) {
          const int bb = gm >> 11, s = gm & 2047;
          const int hh = gn / 192, j = gn - hh * 192;
          const int bh = bb * SH + hh;
          if (j < 64)
            Q[(bh * SS + s) * SHD + j] = f2b(v * 0.125f);
          else if (j < 128)
            K[(bh * SS + s) * SHD + (j - 64)] = f2b(v);
          else
            Vt[(bh * SHD + (j - 128)) * SS + s] = f2b(v);
        } else {
          Out[gm * 512 + gn] = v;
        }
      }
    }
  }
}

// ---------------------------------------------------------------------------
// Fused attention v11 = R10 (single-pass, scores in regs, best at 416.7)
// with the P-store tail changed to FULL-ROW CONTIGUOUS cross-wave stores.
// R11's direct profile: attn write-bound at 1.46 TB/s, VALU 16%, MFMA 5%,
// occupancy 82% — occupancy/spill exonerated; the write stream is the wall.
// The fill does 6.3 TB/s on the SAME buffer; the remaining difference is
// per-writer run length (fill = long monotone runs; our waves emitted 1 KB
// chunks at 8 KB stride). Here: deposit 8 rows fp32 into per-wave LDS,
// barrier, then wave w writes global q-row (8c+w) ENTIRELY — one 8 KB
// pure-sequential run per wave per pass. Bit-identical output.
// ---------------------------------------------------------------------------
#define PSTR 264
#define PWAVE (16 * PSTR)   // u16 elems per wave region (8448 B)
#define OSTR 72             // f32 stride for O-partial staging (16B aligned)

__global__ __launch_bounds__(512, 4)
void attn_kernel(const u16* __restrict__ Q, const u16* __restrict__ K,
                 const u16* __restrict__ Vt, u16* __restrict__ values,
                 float* __restrict__ attn)
{
  __shared__ __align__(16) u16 p_lds[8 * PWAVE];  // 67,584 B
  __shared__ float srm[8][16];
  __shared__ float srl[8][16];

  const int tid  = threadIdx.x;
  const int lane = tid & 63, wave = tid >> 6, quad = lane >> 4, l16 = lane & 15;

  // XCD swizzle: each XCD gets 2 (b,h) pairs x all 128 q-tiles
  const int bid = blockIdx.x;
  const int wg  = (bid & 7) * 256 + (bid >> 3);
  const int qt  = wg & 127;        // q-tile (16 rows)
  const int bh  = wg >> 7;         // 0..15
  const int h = bh & 7, b = bh >> 3;
  const int q0 = qt * 16;

  const u16* Qb = Q + (size_t)bh * SS * SHD;
  const u16* Kb = K + (size_t)bh * SS * SHD;
  const u16* Vb = Vt + (size_t)bh * SHD * SS;

  // Q fragments (B-operand; lane layout same as A)
  const bf16x8 aq0 = as_bf16x8(*(const u16x8*)&Qb[(q0 + l16) * SHD + quad * 8]);
  const bf16x8 aq1 = as_bf16x8(*(const u16x8*)&Qb[(q0 + l16) * SHD + 32 + quad * 8]);

  // ---- scores: acc[ct][r] = S[q = l16][key = ct*16 + quad*4 + r] ----
  f32x4 acc[16];
#pragma unroll
  for (int ct = 0; ct < 16; ct++) {
    const int kb = wave * 256 + ct * 16;
    bf16x8 bk0 = as_bf16x8(*(const u16x8*)&Kb[(kb + l16) * SHD + quad * 8]);
    bf16x8 bk1 = as_bf16x8(*(const u16x8*)&Kb[(kb + l16) * SHD + 32 + quad * 8]);
    f32x4 c = {0.f, 0.f, 0.f, 0.f};
    c = MFMA16(bk0, aq0, c);   // SWAPPED: A=K, B=Q
    c = MFMA16(bk1, aq1, c);
    acc[ct] = c;
  }

  // ---- per-lane stats for row q=l16 (64 in-reg values) ----
  f32x4 mx4 = acc[0];
#pragma unroll
  for (int ct = 1; ct < 16; ct++)
#pragma unroll
    for (int r = 0; r < 4; r++) mx4[r] = fmaxf(mx4[r], acc[ct][r]);
  float m = fmaxf(fmaxf(mx4[0], mx4[1]), fmaxf(mx4[2], mx4[3]));
  m = fmaxf(m, __shfl_xor(m, 16));
  m = fmaxf(m, __shfl_xor(m, 32));

  f32x4 s4 = {0.f, 0.f, 0.f, 0.f};
#pragma unroll
  for (int ct = 0; ct < 16; ct++)
#pragma unroll
    for (int r = 0; r < 4; r++) {
      const float p = __expf(acc[ct][r] - m);
      acc[ct][r] = p;
      s4[r] += p;
    }
  float s = (s4[0] + s4[1]) + (s4[2] + s4[3]);
  s += __shfl_xor(s, 16);
  s += __shfl_xor(s, 32);

  if (lane < 16) {   // quad == 0
    srm[wave][l16] = m;
    srl[wave][l16] = s;
  }
  __syncthreads();  // barrier #1

  // ---- global merge: scale = exp(m_w - m_g) / l_g ----
  float mg = srm[0][l16];
#pragma unroll
  for (int w = 1; w < 8; w++) mg = fmaxf(mg, srm[w][l16]);
  float lg = 0.f;
#pragma unroll
  for (int w = 0; w < 8; w++) lg += srl[w][l16] * __expf(srm[w][l16] - mg);
  const float scale = __expf(m - mg) / lg;
#pragma unroll
  for (int ct = 0; ct < 16; ct++)
#pragma unroll
    for (int r = 0; r < 4; r++) acc[ct][r] *= scale;

  // ---- bf16 P -> wave-private LDS ([q][key], 16x ds_write_b64) ----
  u16* pl = &p_lds[wave * PWAVE];
#pragma unroll
  for (int ct = 0; ct < 16; ct++) {
    u16x4 t;
#pragma unroll
    for (int r = 0; r < 4; r++) t[r] = f2b(acc[ct][r]);
    *(u16x4*)&pl[l16 * PSTR + ct * 16 + quad * 4] = t;
  }

  // ---- PV (swapped: A=V, B=P) with 2-deep V prefetch ----
  f32x4 oacc[4];
#pragma unroll
  for (int nt = 0; nt < 4; nt++) oacc[nt] = (f32x4){0.f, 0.f, 0.f, 0.f};
  bf16x8 vbuf[2][4];
  {
    const int sb = wave * 256 + quad * 8;
#pragma unroll
    for (int nt = 0; nt < 4; nt++)
      vbuf[0][nt] = as_bf16x8(*(const u16x8*)&Vb[(nt * 16 + l16) * SS + sb]);
  }
#pragma unroll
  for (int kc = 0; kc < 8; kc++) {
    if (kc < 7) {
      const int sb = wave * 256 + (kc + 1) * 32 + quad * 8;
#pragma unroll
      for (int nt = 0; nt < 4; nt++)
        vbuf[(kc + 1) & 1][nt] =
            as_bf16x8(*(const u16x8*)&Vb[(nt * 16 + l16) * SS + sb]);
    }
    bf16x8 pa = as_bf16x8(*(const u16x8*)&pl[l16 * PSTR + kc * 32 + quad * 8]);
#pragma unroll
    for (int nt = 0; nt < 4; nt++)
      oacc[nt] = MFMA16(vbuf[kc & 1][nt], pa, oacc[nt]);  // O[q=l16][d]
  }

  // ---- O partials [q][d] into own LDS region (4x ds_write_b128) ----
  float* op = (float*)pl;  // 16*OSTR*4 = 4608 B of 8448 B region
#pragma unroll
  for (int nt = 0; nt < 4; nt++)
    *(f32x4*)&op[l16 * OSTR + nt * 16 + quad * 4] = oacc[nt];
  __syncthreads();  // barrier #2

  // ---- cross-wave reduce + values write ----
  const int q = tid >> 5, d0 = (tid & 31) * 2;
  f32x2 s2 = {0.f, 0.f};
#pragma unroll
  for (int w = 0; w < 8; w++) {
    const float* opw = (const float*)&p_lds[w * PWAVE];
    s2 += *(const f32x2*)&opw[q * OSTR + d0];
  }
  u16x2 o2;
  o2[0] = f2b(s2[0]);
  o2[1] = f2b(s2[1]);
  *(u16x2*)&values[((size_t)(b * SS + q0 + q) * SH + h) * SHD + d0] = o2;

  __syncthreads();  // barrier #3: all waves done reading op regions

  // ---- LAST: fp32 P via LDS bounce -> FULL-ROW 8 KB sequential stores ----
  // Pass c: holder lanes deposit rows 8c..8c+7 fp32 (own 256-col strip) into
  // their wave region; barrier; then wave w stitches global q-row (8c+w)
  // across ALL 8 wave regions and writes it as ONE 8 KB contiguous run
  // (8 x 1 KB instructions at consecutive addresses) — fill-like per-wave
  // address streams. XOR swizzle (colf^row) keeps both LDS phases cheap.
  float* attn_b = attn + ((size_t)bh * SS + q0) * SS;
#pragma unroll
  for (int c = 0; c < 2; c++) {
    if ((l16 >> 3) == c) {
      const int row = l16 & 7;
      float* bb2 = (float*)pl;
#pragma unroll
      for (int ct = 0; ct < 16; ct++) {
        const int colf = ct * 4 + quad;                  // 16B block in [0,64)
        *(f32x4*)&bb2[row * 256 + ((colf ^ row) * 4)] = acc[ct];
      }
    }
    __syncthreads();  // deposits visible to all waves
    {
      const int row = wave;    // this wave owns global q-row (c*8 + wave)
#pragma unroll
      for (int seg = 0; seg < 8; seg++) {
        const float* src = (const float*)&p_lds[seg * PWAVE];
        const f32x4 v = *(const f32x4*)&src[row * 256 + ((lane ^ row) * 4)];
        *(f32x4*)&attn_b[(size_t)(c * 8 + row) * SS + seg * 256 + lane * 4] = v;
      }
    }
    if (c == 0) __syncthreads();  // WAR: regions reused by pass-1 deposits
  }
}

// ---------------------------------------------------------------------------
// Workspace budget: EXACTLY 16 MiB (verified footprint).
//   ws: Q(4MB) K(4MB) Vt(4MB) values(4MB; Xb aliases it)
//   WqkvT: staged in d_out's attn region (dead until attn_kernel overwrites).
//   WoT:   aliases Q region; produced AFTER attn (Q dead), read by oproj.
// ---------------------------------------------------------------------------
extern "C" void kernel_launch(void* const* d_in, const int* in_sizes, int n_in,
                              void* d_out, int out_size, void* d_ws, size_t ws_size,
                              hipStream_t stream) {
  const float* X    = (const float*)d_in[0];
  const float* Wqkv = (const float*)d_in[1];
  const float* bqkv = (const float*)d_in[2];
  const float* Wo   = (const float*)d_in[3];
  const float* bo   = (const float*)d_in[4];

  float* o_out    = (float*)d_out;                       // [2,2048,512]
  float* attn_out = o_out + SB * SS * SE;                // [2,8,2048,2048]

  const size_t QKV_ELEMS = (size_t)SB * SH * SS * SHD;   // 2,097,152 per tensor
  u16* Q      = (u16*)d_ws;
  u16* K      = Q + QKV_ELEMS;
  u16* Vt     = K + QKV_ELEMS;
  u16* values = Vt + QKV_ELEMS;
  u16* Xb     = values;               // dead before attn writes values
  u16* WqkvT  = (u16*)attn_out;       // dead until attn writes attn_out
  u16* WoT    = Q;                    // Q dead after attn; WoT made post-attn

  // Merged prep: X conversion + Wqkv transpose (one launch)
  prep_kernel<<<dim3(2816), 256, 0, stream>>>(X, Xb, Wqkv, WqkvT);

  // QKV projection: M=4096 (32 m-blocks), N=1536 (12 n-blocks)
  gemm_kernel<0><<<dim3(12, 32), 256, 0, stream>>>(Xb, WqkvT, bqkv, Q, K, Vt, nullptr);
  // Attention: 2048 blocks, XCD-swizzled
  attn_kernel<<<dim3(2048), 512, 0, stream>>>(Q, K, Vt, values, attn_out);
  // Wo transpose into (now-dead) Q region, then O projection
  wtrans_kernel<<<dim3(16, 16), 256, 0, stream>>>(Wo, WoT, 512);
  gemm_kernel<1><<<dim3(4, 32), 256, 0, stream>>>(values, WoT, bo,
                                                  nullptr, nullptr, nullptr, o_out);
}